// Round 5
// baseline (285.376 us; speedup 1.0000x reference)
//
#include <hip/hip_runtime.h>

#define IH 256
#define IW 256
#define FH 128
#define FW 128
#define NB 16
#define ICH 33
#define NF 10
#define NC 30          // warped channels = NF*3
#define PL (FH * FW)   // 16384
#define ACC_ZERO 3856                      // floats zeroed: acc_bc 3840 + acc_g 8 + counter/pad
#define SMOOTH_BLK 1280
#define RES_BLK (NB * ICH * 64)            // 33792 row-pair blocks
#define RES_OFF 8192                       // floats offset of resized in ws
#define RES_CNT (NB * ICH * PL)            // 8,650,752 floats
#define WS_NEED ((size_t)(RES_OFF + RES_CNT) * 4)

// fast exact charbonnier: (g^2 + 1e-6)^0.4, arg > 0 so hw log/exp safe (~1ulp)
__device__ __forceinline__ float charb(float g) {
    float t = fmaf(g, g, 1e-6f);
    return __builtin_amdgcn_exp2f(0.4f * __builtin_amdgcn_logf(t));
}

// ============ K1: smooth partials (blocks [0,1280)) + resize (blocks [1280,35072)) ====
// Block 0 additionally zero-inits the accumulator region (safe: all atomics are in K2;
// smooth blocks write only their own partial slots).
__global__ void __launch_bounds__(256) k1_smooth_resize(const float* __restrict__ images,
                                                        const float* __restrict__ flows,
                                                        float* __restrict__ ws)
{
    float* acc         = ws;               // [3856] zeroed here
    float* smooth_part = ws + ACC_ZERO;    // [1280] partials, no init needed
    float* resized     = ws + RES_OFF;

    if (blockIdx.x == 0) {
        for (int i = threadIdx.x; i < ACC_ZERO; i += 256) acc[i] = 0.f;
    }

    if (blockIdx.x < SMOOTH_BLK) {
        // ---- smoothness partial: gradient along flow-index axis and H axis ----
        const int total = NB * NF * PL;
        float s = 0.f;
        for (int i = blockIdx.x * 256 + threadIdx.x; i < total; i += SMOOTH_BLK * 256) {
            int w = i & (FW - 1);
            int h = (i >> 7) & (FH - 1);
            int f = (i >> 14) % NF;
            int b = i / (NF * PL);
            int pix = h * FW + w;
            const float* xp = flows + (size_t)(b * 2 * NF + 2 * f) * PL;
            const float* yp = xp + PL;

            float g1x, g1y;   // flow-channel axis (stride 2 planes)
            if (f == 0)           { g1x = xp[2 * PL + pix] - xp[pix];
                                    g1y = yp[2 * PL + pix] - yp[pix]; }
            else if (f == NF - 1) { g1x = xp[pix] - xp[pix - 2 * PL];
                                    g1y = yp[pix] - yp[pix - 2 * PL]; }
            else                  { g1x = 0.5f * (xp[2 * PL + pix] - xp[pix - 2 * PL]);
                                    g1y = 0.5f * (yp[2 * PL + pix] - yp[pix - 2 * PL]); }

            float g2x, g2y;   // H axis
            if (h == 0)           { g2x = xp[pix + FW] - xp[pix];
                                    g2y = yp[pix + FW] - yp[pix]; }
            else if (h == FH - 1) { g2x = xp[pix] - xp[pix - FW];
                                    g2y = yp[pix] - yp[pix - FW]; }
            else                  { g2x = 0.5f * (xp[pix + FW] - xp[pix - FW]);
                                    g2y = 0.5f * (yp[pix + FW] - yp[pix - FW]); }

            s += charb(g1x) + charb(g2x) + charb(g1y) + charb(g2y);
        }
        for (int off = 32; off > 0; off >>= 1) s += __shfl_down(s, off, 64);
        __shared__ float shs[4];
        int wave = threadIdx.x >> 6;
        if ((threadIdx.x & 63) == 0) shs[wave] = s;
        __syncthreads();
        if (threadIdx.x == 0)
            smooth_part[blockIdx.x] = shs[0] + shs[1] + shs[2] + shs[3];
        return;
    }

    // ---- LDS-staged resize: one block = one plane row-pair (2x128 out px) ----
    int rb = blockIdx.x - SMOOTH_BLK;
    __shared__ float rows[4][256];
    const float s = (float)(255.0 / 127.0);
    int plane = rb >> 6;                   // 64 row-pairs per plane
    int j = rb & 63;
    int h0 = 2 * j;
    int y0a = (int)((float)h0 * s);       if (y0a > IH - 2) y0a = IH - 2;
    int y0b = (int)((float)(h0 + 1) * s); if (y0b > IH - 2) y0b = IH - 2;
    const float* pin = images + (size_t)plane * (IH * IW);
    int r = threadIdx.x >> 6;
    int l = threadIdx.x & 63;
    int yr = (r < 2 ? y0a : y0b) + (r & 1);
    const float4* srcv = (const float4*)(pin + yr * IW);
    ((float4*)rows[r])[l] = srcv[l];
    __syncthreads();
    int lr = threadIdx.x >> 7;
    int w = threadIdx.x & 127;
    int h = h0 + lr;
    float fy = (float)h * s;
    int y0 = lr ? y0b : y0a;
    float wy = fy - (float)y0;
    float fx = (float)w * s;
    int x0 = (int)fx; if (x0 > IW - 2) x0 = IW - 2;
    float wx = fx - (float)x0;
    float v00 = rows[2 * lr][x0],     v01 = rows[2 * lr][x0 + 1];
    float v10 = rows[2 * lr + 1][x0], v11 = rows[2 * lr + 1][x0 + 1];
    float r0 = v00 * (1.f - wy) + v10 * wy;     // y-interp first (matches reference)
    float r1 = v01 * (1.f - wy) + v11 * wy;
    resized[(size_t)plane * PL + h * FW + w] = r0 * (1.f - wx) + r1 * wx;
}

__device__ __forceinline__ float warp_sample(const float* __restrict__ src_plane,
                                             float gx, float gy) {
    float x0f = floorf(gx), y0f = floorf(gy);
    float wx = gx - x0f, wy = gy - y0f;
    int x0 = (int)x0f; x0 = min(max(x0, 0), FW - 1);
    int y0 = (int)y0f; y0 = min(max(y0, 0), FH - 1);
    int x1 = min(x0 + 1, FW - 1);
    int y1 = min(y0 + 1, FH - 1);
    const float* r0p = src_plane + y0 * FW;
    const float* r1p = src_plane + y1 * FW;
    float v00 = r0p[x0], v01 = r0p[x1];
    float v10 = r1p[x0], v11 = r1p[x1];
    float top = v00 * (1.f - wx) + v01 * wx;
    float bot = v10 * (1.f - wx) + v11 * wx;
    return top * (1.f - wy) + bot * wy;
}

// ============ K2: loss (1920 blocks, XCD-swizzled) + last-block finalize ============
#define SPLIT 4
#define LOSS_BLOCKS (NB * NC * SPLIT)      // 1920
#define PIX_PER_BLOCK (PL / SPLIT)         // 4096
__global__ void __launch_bounds__(256) k2_loss_final(const float* __restrict__ flows,
                                                     float* __restrict__ ws,
                                                     float* __restrict__ out)
{
    float* acc_bc      = ws;                          // [480][8]
    float* acc_g       = ws + 3840;                   // [8]: [0]=pixel charb sum
    unsigned* counter  = (unsigned*)(ws + 3848);      // zeroed by K1
    const float* smooth_part = ws + ACC_ZERO;         // [1280] from K1
    const float* resized     = ws + RES_OFF;

    // XCD swizzle: xcd = blockIdx&7 owns batches {xcd, xcd+8}; reused src planes
    // per XCD = 2 x 1.9 MB -> fits 4 MB per-XCD L2.
    int xcd  = blockIdx.x & 7;
    int slot = blockIdx.x >> 3;            // 0..239
    int hi   = (slot >= 120) ? 1 : 0;
    int b    = xcd + 8 * hi;
    int j    = slot - 120 * hi;            // 0..119
    int c    = j >> 2;
    int part = j & 3;
    int bc   = b * NC + c;
    int f    = c / 3;

    const float* ref_plane = resized + (size_t)(b * ICH + c) * PL;
    const float* src_plane = resized + (size_t)(b * ICH + 3 + c) * PL;
    const float* fx_plane  = flows + (size_t)(b * 2 * NF + 2 * f) * PL;
    const float* fy_plane  = fx_plane + PL;

    float s_ref = 0.f, s_w = 0.f, s_r2 = 0.f, s_w2 = 0.f, s_rw = 0.f, s_pix = 0.f;
    int base4 = part * (PIX_PER_BLOCK / 4);           // float4 index base
    for (int i = threadIdx.x; i < PIX_PER_BLOCK / 4; i += 256) {
        int p4 = base4 + i;
        int pix = p4 * 4;
        int h = pix >> 7;
        int w = pix & (FW - 1);                        // multiple of 4, w+3 <= 127
        float4 r4 = ((const float4*)ref_plane)[p4];
        float4 fx4 = ((const float4*)fx_plane)[p4];
        float4 fy4 = ((const float4*)fy_plane)[p4];
        float fh = (float)h, fw0 = (float)w;

        float wv0 = warp_sample(src_plane, fw0 + fx4.x,       fh + fy4.x);
        float wv1 = warp_sample(src_plane, fw0 + 1.f + fx4.y, fh + fy4.y);
        float wv2 = warp_sample(src_plane, fw0 + 2.f + fx4.z, fh + fy4.z);
        float wv3 = warp_sample(src_plane, fw0 + 3.f + fx4.w, fh + fy4.w);

        s_ref += (r4.x + r4.y) + (r4.z + r4.w);
        s_w   += (wv0 + wv1) + (wv2 + wv3);
        s_r2  += r4.x * r4.x + r4.y * r4.y + r4.z * r4.z + r4.w * r4.w;
        s_w2  += wv0 * wv0 + wv1 * wv1 + wv2 * wv2 + wv3 * wv3;
        s_rw  += r4.x * wv0 + r4.y * wv1 + r4.z * wv2 + r4.w * wv3;
        s_pix += charb(r4.x - wv0) + charb(r4.y - wv1)
               + charb(r4.z - wv2) + charb(r4.w - wv3);
    }
    for (int off = 32; off > 0; off >>= 1) {
        s_ref += __shfl_down(s_ref, off, 64);
        s_w   += __shfl_down(s_w, off, 64);
        s_r2  += __shfl_down(s_r2, off, 64);
        s_w2  += __shfl_down(s_w2, off, 64);
        s_rw  += __shfl_down(s_rw, off, 64);
        s_pix += __shfl_down(s_pix, off, 64);
    }
    __shared__ float sh[4][6];
    __shared__ int last_flag;
    int wave = threadIdx.x >> 6;
    if ((threadIdx.x & 63) == 0) {
        sh[wave][0] = s_ref; sh[wave][1] = s_w; sh[wave][2] = s_r2;
        sh[wave][3] = s_w2;  sh[wave][4] = s_rw; sh[wave][5] = s_pix;
    }
    __syncthreads();
    if (threadIdx.x == 0) {
        float t0 = 0, t1 = 0, t2 = 0, t3 = 0, t4 = 0, t5 = 0;
        for (int v = 0; v < 4; v++) {
            t0 += sh[v][0]; t1 += sh[v][1]; t2 += sh[v][2];
            t3 += sh[v][3]; t4 += sh[v][4]; t5 += sh[v][5];
        }
        float* a = acc_bc + bc * 8;
        atomicAdd(a + 0, t0);
        atomicAdd(a + 1, t1);
        atomicAdd(a + 2, t2);
        atomicAdd(a + 3, t3);
        atomicAdd(a + 4, t4);
        atomicAdd(acc_g + 0, t5);
        __threadfence();
        unsigned old = atomicAdd(counter, 1u);
        last_flag = (old == LOSS_BLOCKS - 1) ? 1 : 0;
    }
    __syncthreads();
    if (!last_flag) return;

    // ---- last block: SSIM per (b,c) + combine to scalar ----
    float ssim_s = 0.f;
    for (int e = threadIdx.x; e < NB * NC; e += 256) {
        float* a = acc_bc + e * 8;
        float t0 = atomicAdd(a + 0, 0.f);       // atomic reads: device-coherent
        float t1 = atomicAdd(a + 1, 0.f);
        float t2 = atomicAdd(a + 2, 0.f);
        float t3 = atomicAdd(a + 3, 0.f);
        float t4 = atomicAdd(a + 4, 0.f);
        const float N = (float)PL;
        float mu1 = t0 / N, mu2 = t1 / N;
        float var1 = (t2 - t0 * mu1) / (N - 1.f);
        float var2 = (t3 - t1 * mu2) / (N - 1.f);
        float s12 = t4 / N - mu1 * mu2;
        float num = (2.f * mu1 * mu2 + 1e-4f) * (2.f * s12 + 1e-3f);
        float den = (mu1 * mu1 + mu2 * mu2 + 1e-4f) * (var1 + var2 + 1e-3f);
        ssim_s += num / den;
    }
    float smooth_s = 0.f;
    for (int i = threadIdx.x; i < SMOOTH_BLK; i += 256)
        smooth_s += smooth_part[i];             // written in K1: visible

    for (int off = 32; off > 0; off >>= 1) {
        ssim_s   += __shfl_down(ssim_s, off, 64);
        smooth_s += __shfl_down(smooth_s, off, 64);
    }
    __shared__ float fs[4][2];
    if ((threadIdx.x & 63) == 0) { fs[wave][0] = ssim_s; fs[wave][1] = smooth_s; }
    __syncthreads();
    if (threadIdx.x == 0) {
        float ssim_t = fs[0][0] + fs[1][0] + fs[2][0] + fs[3][0];
        float smo_t  = fs[0][1] + fs[1][1] + fs[2][1] + fs[3][1];
        float pix_t  = atomicAdd(acc_g + 0, 0.f);
        out[0] = pix_t / (float)(NB * NC * PL)
               + 0.01f * (smo_t / (float)(NB * NF * PL))
               + ssim_t / (float)(NB * NC);
    }
}

// ================= Fallback (no-workspace) path =================
__device__ __forceinline__ float resized_at(const float* __restrict__ plane, int Y, int X) {
    const float s = (float)(255.0 / 127.0);
    float fy = (float)Y * s;
    float fx = (float)X * s;
    int y0 = (int)fy; y0 = y0 > IH - 2 ? IH - 2 : y0;
    int x0 = (int)fx; x0 = x0 > IW - 2 ? IW - 2 : x0;
    float wy = fy - (float)y0;
    float wx = fx - (float)x0;
    const float* p0 = plane + y0 * IW + x0;
    float v00 = p0[0], v01 = p0[1];
    float v10 = p0[IW], v11 = p0[IW + 1];
    float r0 = v00 * (1.f - wy) + v10 * wy;
    float r1 = v01 * (1.f - wy) + v11 * wy;
    return r0 * (1.f - wx) + r1 * wx;
}

__global__ void __launch_bounds__(256) loss_main_fb(const float* __restrict__ images,
                                                    const float* __restrict__ flows,
                                                    float* __restrict__ acc_bc,
                                                    float* __restrict__ acc_g)
{
    int bc = blockIdx.x / 8;
    int part = blockIdx.x % 8;
    int b = bc / NC;
    int c = bc % NC;
    int f = c / 3;
    const float* ref_plane = images + (size_t)(b * ICH + c) * (IH * IW);
    const float* src_plane = images + (size_t)(b * ICH + 3 + c) * (IH * IW);
    const float* fx_plane  = flows + (size_t)(b * 2 * NF + 2 * f) * PL;
    const float* fy_plane  = fx_plane + PL;
    float s_ref = 0.f, s_w = 0.f, s_r2 = 0.f, s_w2 = 0.f, s_rw = 0.f, s_pix = 0.f;
    int base = part * (PL / 8);
    for (int i = threadIdx.x; i < PL / 8; i += 256) {
        int pix = base + i;
        int h = pix >> 7;
        int w = pix & (FW - 1);
        float ref = resized_at(ref_plane, h, w);
        float gx = (float)w + fx_plane[pix];
        float gy = (float)h + fy_plane[pix];
        float x0f = floorf(gx), y0f = floorf(gy);
        float wx = gx - x0f, wy = gy - y0f;
        int x0 = (int)x0f; x0 = min(max(x0, 0), FW - 1);
        int y0 = (int)y0f; y0 = min(max(y0, 0), FH - 1);
        int x1 = min(x0 + 1, FW - 1);
        int y1 = min(y0 + 1, FH - 1);
        float v00 = resized_at(src_plane, y0, x0);
        float v01 = resized_at(src_plane, y0, x1);
        float v10 = resized_at(src_plane, y1, x0);
        float v11 = resized_at(src_plane, y1, x1);
        float top = v00 * (1.f - wx) + v01 * wx;
        float bot = v10 * (1.f - wx) + v11 * wx;
        float wv = top * (1.f - wy) + bot * wy;
        s_ref += ref; s_w += wv;
        s_r2 += ref * ref; s_w2 += wv * wv; s_rw += ref * wv;
        s_pix += charb(ref - wv);
    }
    for (int off = 32; off > 0; off >>= 1) {
        s_ref += __shfl_down(s_ref, off, 64);
        s_w   += __shfl_down(s_w, off, 64);
        s_r2  += __shfl_down(s_r2, off, 64);
        s_w2  += __shfl_down(s_w2, off, 64);
        s_rw  += __shfl_down(s_rw, off, 64);
        s_pix += __shfl_down(s_pix, off, 64);
    }
    if ((threadIdx.x & 63) == 0) {
        float* a = acc_bc + bc * 8;
        atomicAdd(a + 0, s_ref);
        atomicAdd(a + 1, s_w);
        atomicAdd(a + 2, s_r2);
        atomicAdd(a + 3, s_w2);
        atomicAdd(a + 4, s_rw);
        atomicAdd(acc_g + 0, s_pix);
    }
}

__global__ void __launch_bounds__(256) smooth_fb(const float* __restrict__ flows,
                                                 float* __restrict__ acc_g)
{
    const int total = NB * NF * PL;
    float s = 0.f;
    for (int i = blockIdx.x * 256 + threadIdx.x; i < total; i += 1280 * 256) {
        int w = i & (FW - 1);
        int h = (i >> 7) & (FH - 1);
        int f = (i >> 14) % NF;
        int b = i / (NF * PL);
        int pix = h * FW + w;
        const float* xp = flows + (size_t)(b * 2 * NF + 2 * f) * PL;
        const float* yp = xp + PL;
        float g1x, g1y;
        if (f == 0)           { g1x = xp[2 * PL + pix] - xp[pix];
                                g1y = yp[2 * PL + pix] - yp[pix]; }
        else if (f == NF - 1) { g1x = xp[pix] - xp[pix - 2 * PL];
                                g1y = yp[pix] - yp[pix - 2 * PL]; }
        else                  { g1x = 0.5f * (xp[2 * PL + pix] - xp[pix - 2 * PL]);
                                g1y = 0.5f * (yp[2 * PL + pix] - yp[pix - 2 * PL]); }
        float g2x, g2y;
        if (h == 0)           { g2x = xp[pix + FW] - xp[pix];
                                g2y = yp[pix + FW] - yp[pix]; }
        else if (h == FH - 1) { g2x = xp[pix] - xp[pix - FW];
                                g2y = yp[pix] - yp[pix - FW]; }
        else                  { g2x = 0.5f * (xp[pix + FW] - xp[pix - FW]);
                                g2y = 0.5f * (yp[pix + FW] - yp[pix - FW]); }
        s += charb(g1x) + charb(g2x) + charb(g1y) + charb(g2y);
    }
    for (int off = 32; off > 0; off >>= 1) s += __shfl_down(s, off, 64);
    __shared__ float sh[4];
    int wave = threadIdx.x >> 6;
    if ((threadIdx.x & 63) == 0) sh[wave] = s;
    __syncthreads();
    if (threadIdx.x == 0)
        atomicAdd(acc_g + 2, sh[0] + sh[1] + sh[2] + sh[3]);
}

__global__ void __launch_bounds__(512) finalize_fb(const float* __restrict__ acc_bc,
                                                   const float* __restrict__ acc_g,
                                                   float* __restrict__ out)
{
    __shared__ float sh[512];
    int tid = threadIdx.x;
    float ssim = 0.f;
    if (tid < NB * NC) {
        const float* a = acc_bc + tid * 8;
        const float N = (float)PL;
        float mu1 = a[0] / N, mu2 = a[1] / N;
        float var1 = (a[2] - a[0] * mu1) / (N - 1.f);
        float var2 = (a[3] - a[1] * mu2) / (N - 1.f);
        float s12 = a[4] / N - mu1 * mu2;
        float num = (2.f * mu1 * mu2 + 1e-4f) * (2.f * s12 + 1e-3f);
        float den = (mu1 * mu1 + mu2 * mu2 + 1e-4f) * (var1 + var2 + 1e-3f);
        ssim = num / den;
    }
    sh[tid] = ssim;
    __syncthreads();
    for (int off = 256; off > 0; off >>= 1) {
        if (tid < off) sh[tid] += sh[tid + off];
        __syncthreads();
    }
    if (tid == 0) {
        out[0] = acc_g[0] / (float)(NB * NC * PL)
               + 0.01f * (acc_g[2] / (float)(NB * NF * PL))
               + sh[0] / (float)(NB * NC);
    }
}

extern "C" void kernel_launch(void* const* d_in, const int* in_sizes, int n_in,
                              void* d_out, int out_size, void* d_ws, size_t ws_size,
                              hipStream_t stream) {
    const float* images = (const float*)d_in[0];
    const float* flows  = (const float*)d_in[1];
    float* ws = (float*)d_ws;
    if (ws_size >= WS_NEED) {
        k1_smooth_resize<<<SMOOTH_BLK + RES_BLK, 256, 0, stream>>>(images, flows, ws);
        k2_loss_final<<<LOSS_BLOCKS, 256, 0, stream>>>(flows, ws, (float*)d_out);
    } else {
        float* acc_bc = ws;
        float* acc_g  = ws + 3840;
        (void)hipMemsetAsync(d_ws, 0, ACC_ZERO * sizeof(float), stream);
        loss_main_fb<<<NB * NC * 8, 256, 0, stream>>>(images, flows, acc_bc, acc_g);
        smooth_fb<<<1280, 256, 0, stream>>>(flows, acc_g);
        finalize_fb<<<1, 512, 0, stream>>>(acc_bc, acc_g, (float*)d_out);
    }
}

// Round 6
// 253.464 us; speedup vs baseline: 1.1259x; 1.1259x over previous
//
#include <hip/hip_runtime.h>

#define IH 256
#define IW 256
#define FH 128
#define FW 128
#define NB 16
#define ICH 33
#define NF 10
#define NC 30            // warped channels = NF*3
#define PL (FH * FW)     // 16384
#define LOSS_BLOCKS (NB * NC * 2)          // 960: 2 half-plane parts per (b,c)
#define SMOOTH_BLOCKS 240
#define HALO 7
#define SROWS (64 + 2 * HALO + 1)          // 79 rows staged -> 40448 B LDS (4 blocks/CU)
#define PART_STRIDE 8

// fast exact charbonnier: (g^2 + 1e-6)^0.4, arg > 0 so hw log2/exp2 safe (~1ulp)
__device__ __forceinline__ float charb(float g) {
    float t = fmaf(g, g, 1e-6f);
    return __builtin_amdgcn_exp2f(0.4f * __builtin_amdgcn_logf(t));
}

// align-corners bilinear sample of a 256x256 plane at 128-grid point (Y,X).
// Bit-exact vs jax reference (verified absmax 0.0 rounds 3-5).
__device__ __forceinline__ float resized_at(const float* __restrict__ plane, int Y, int X) {
    const float s = (float)(255.0 / 127.0);
    float fy = (float)Y * s;
    float fx = (float)X * s;
    int y0 = (int)fy; y0 = y0 > IH - 2 ? IH - 2 : y0;
    int x0 = (int)fx; x0 = x0 > IW - 2 ? IW - 2 : x0;
    float wy = fy - (float)y0;
    float wx = fx - (float)x0;
    const float* p0 = plane + y0 * IW + x0;
    float v00 = p0[0], v01 = p0[1];
    float v10 = p0[IW], v11 = p0[IW + 1];
    float r0 = v00 * (1.f - wy) + v10 * wy;   // y-interp first (matches reference)
    float r1 = v01 * (1.f - wy) + v11 * wy;
    return r0 * (1.f - wx) + r1 * wx;
}

// ================== Mega kernel: loss (960 blocks) + smooth (240 blocks) ==============
// No atomics anywhere: each block plain-stores its partial sums; finalize reads them
// in a second dispatch (kernel boundary = coherence point). No zero-init required.
__global__ void __launch_bounds__(256) mega(const float* __restrict__ images,
                                            const float* __restrict__ flows,
                                            float* __restrict__ ws)
{
    float* part_loss   = ws;                                // [960][8]
    float* part_smooth = ws + LOSS_BLOCKS * PART_STRIDE;    // [240]

    if (blockIdx.x >= LOSS_BLOCKS) {
        // ---------- smoothness partial: gradient along flow-index axis and H axis ----
        int sb = blockIdx.x - LOSS_BLOCKS;
        const int total = NB * NF * PL;
        float s = 0.f;
        for (int i = sb * 256 + threadIdx.x; i < total; i += SMOOTH_BLOCKS * 256) {
            int w = i & (FW - 1);
            int h = (i >> 7) & (FH - 1);
            int f = (i >> 14) % NF;
            int b = i / (NF * PL);
            int pix = h * FW + w;
            const float* xp = flows + (size_t)(b * 2 * NF + 2 * f) * PL;
            const float* yp = xp + PL;

            float g1x, g1y;   // flow-channel axis (stride 2 planes)
            if (f == 0)           { g1x = xp[2 * PL + pix] - xp[pix];
                                    g1y = yp[2 * PL + pix] - yp[pix]; }
            else if (f == NF - 1) { g1x = xp[pix] - xp[pix - 2 * PL];
                                    g1y = yp[pix] - yp[pix - 2 * PL]; }
            else                  { g1x = 0.5f * (xp[2 * PL + pix] - xp[pix - 2 * PL]);
                                    g1y = 0.5f * (yp[2 * PL + pix] - yp[pix - 2 * PL]); }

            float g2x, g2y;   // H axis
            if (h == 0)           { g2x = xp[pix + FW] - xp[pix];
                                    g2y = yp[pix + FW] - yp[pix]; }
            else if (h == FH - 1) { g2x = xp[pix] - xp[pix - FW];
                                    g2y = yp[pix] - yp[pix - FW]; }
            else                  { g2x = 0.5f * (xp[pix + FW] - xp[pix - FW]);
                                    g2y = 0.5f * (yp[pix + FW] - yp[pix - FW]); }

            s += charb(g1x) + charb(g2x) + charb(g1y) + charb(g2y);
        }
        for (int off = 32; off > 0; off >>= 1) s += __shfl_down(s, off, 64);
        __shared__ float shs[4];
        int wave = threadIdx.x >> 6;
        if ((threadIdx.x & 63) == 0) shs[wave] = s;
        __syncthreads();
        if (threadIdx.x == 0)
            part_smooth[sb] = shs[0] + shs[1] + shs[2] + shs[3];
        return;
    }

    // ---------- loss block: (bc, half-plane part) ----------
    __shared__ float slds[SROWS * FW];     // resized src half-plane + halo
    int blk = blockIdx.x;
    int bc = blk >> 1;
    int p  = blk & 1;
    int b = bc / NC;
    int c = bc % NC;
    int f = c / 3;
    const float* ref_img  = images + (size_t)(b * ICH + c) * (IH * IW);
    const float* src_img  = images + (size_t)(b * ICH + 3 + c) * (IH * IW);
    const float* fx_plane = flows + (size_t)(b * 2 * NF + 2 * f) * PL;
    const float* fy_plane = fx_plane + PL;

    int lo = p * 64 - HALO;          if (lo < 0) lo = 0;
    int hi = p * 64 + 63 + HALO + 1; if (hi > FH - 1) hi = FH - 1;
    int nstage = (hi - lo + 1) * FW;

    // stage: resize src rows [lo,hi] into LDS (consecutive writes, conflict-free)
    for (int i = threadIdx.x; i < nstage; i += 256) {
        int y = lo + (i >> 7);
        int x = i & (FW - 1);
        slds[i] = resized_at(src_img, y, x);
    }
    __syncthreads();

    float s_ref = 0.f, s_w = 0.f, s_r2 = 0.f, s_w2 = 0.f, s_rw = 0.f, s_pix = 0.f;
    int base = p * 8192;
    for (int i = threadIdx.x; i < 8192; i += 256) {
        int px = base + i;
        int h = px >> 7;
        int w = px & (FW - 1);
        float ref = resized_at(ref_img, h, w);
        float gx = (float)w + fx_plane[px];
        float gy = (float)h + fy_plane[px];
        float x0f = floorf(gx), y0f = floorf(gy);
        float wx = gx - x0f, wy = gy - y0f;
        int x0 = (int)x0f; x0 = min(max(x0, 0), FW - 1);
        int y0 = (int)y0f; y0 = min(max(y0, 0), FH - 1);
        int x1 = min(x0 + 1, FW - 1);
        int y1 = min(y0 + 1, FH - 1);
        float v00, v01, v10, v11;
        if (y0 >= lo && y1 <= hi) {    // always true unless |flow| > 7 sigma
            const float* r0 = slds + ((y0 - lo) << 7);
            const float* r1 = slds + ((y1 - lo) << 7);
            v00 = r0[x0]; v01 = r0[x1];
            v10 = r1[x0]; v11 = r1[x1];
        } else {                        // exact recompute from global (rare/never)
            v00 = resized_at(src_img, y0, x0);
            v01 = resized_at(src_img, y0, x1);
            v10 = resized_at(src_img, y1, x0);
            v11 = resized_at(src_img, y1, x1);
        }
        float top = v00 * (1.f - wx) + v01 * wx;
        float bot = v10 * (1.f - wx) + v11 * wx;
        float wv = top * (1.f - wy) + bot * wy;

        s_ref += ref; s_w += wv;
        s_r2 += ref * ref; s_w2 += wv * wv; s_rw += ref * wv;
        s_pix += charb(ref - wv);
    }
    for (int off = 32; off > 0; off >>= 1) {
        s_ref += __shfl_down(s_ref, off, 64);
        s_w   += __shfl_down(s_w, off, 64);
        s_r2  += __shfl_down(s_r2, off, 64);
        s_w2  += __shfl_down(s_w2, off, 64);
        s_rw  += __shfl_down(s_rw, off, 64);
        s_pix += __shfl_down(s_pix, off, 64);
    }
    __shared__ float sh[4][6];
    int wave = threadIdx.x >> 6;
    if ((threadIdx.x & 63) == 0) {
        sh[wave][0] = s_ref; sh[wave][1] = s_w; sh[wave][2] = s_r2;
        sh[wave][3] = s_w2;  sh[wave][4] = s_rw; sh[wave][5] = s_pix;
    }
    __syncthreads();
    if (threadIdx.x < 6) {
        int k = threadIdx.x;
        part_loss[blk * PART_STRIDE + k] =
            sh[0][k] + sh[1][k] + sh[2][k] + sh[3][k];
    }
}

// ================== finalize: SSIM per (b,c) + combine to scalar ==================
__global__ void __launch_bounds__(512) finalize2(const float* __restrict__ ws,
                                                 float* __restrict__ out)
{
    const float* part_loss   = ws;
    const float* part_smooth = ws + LOSS_BLOCKS * PART_STRIDE;
    int tid = threadIdx.x;
    float ssim = 0.f, pix = 0.f, smo = 0.f;
    if (tid < NB * NC) {
        const float* a0 = part_loss + (2 * tid) * PART_STRIDE;
        const float* a1 = a0 + PART_STRIDE;
        float t0 = a0[0] + a1[0];
        float t1 = a0[1] + a1[1];
        float t2 = a0[2] + a1[2];
        float t3 = a0[3] + a1[3];
        float t4 = a0[4] + a1[4];
        pix = a0[5] + a1[5];
        const float N = (float)PL;
        float mu1 = t0 / N, mu2 = t1 / N;
        float var1 = (t2 - t0 * mu1) / (N - 1.f);
        float var2 = (t3 - t1 * mu2) / (N - 1.f);
        float s12 = t4 / N - mu1 * mu2;
        float num = (2.f * mu1 * mu2 + 1e-4f) * (2.f * s12 + 1e-3f);
        float den = (mu1 * mu1 + mu2 * mu2 + 1e-4f) * (var1 + var2 + 1e-3f);
        ssim = num / den;
    }
    if (tid < SMOOTH_BLOCKS) smo = part_smooth[tid];
    __shared__ float sa[512], sb[512], sc[512];
    sa[tid] = ssim; sb[tid] = pix; sc[tid] = smo;
    __syncthreads();
    for (int off = 256; off > 0; off >>= 1) {
        if (tid < off) {
            sa[tid] += sa[tid + off];
            sb[tid] += sb[tid + off];
            sc[tid] += sc[tid + off];
        }
        __syncthreads();
    }
    if (tid == 0) {
        out[0] = sb[0] / (float)(NB * NC * PL)
               + 0.01f * (sc[0] / (float)(NB * NF * PL))
               + sa[0] / (float)(NB * NC);
    }
}

extern "C" void kernel_launch(void* const* d_in, const int* in_sizes, int n_in,
                              void* d_out, int out_size, void* d_ws, size_t ws_size,
                              hipStream_t stream) {
    const float* images = (const float*)d_in[0];
    const float* flows  = (const float*)d_in[1];
    float* ws = (float*)d_ws;   // needs only ~32 KB: plain-stored partials
    mega<<<LOSS_BLOCKS + SMOOTH_BLOCKS, 256, 0, stream>>>(images, flows, ws);
    finalize2<<<1, 512, 0, stream>>>(ws, (float*)d_out);
}

// Round 7
// 233.002 us; speedup vs baseline: 1.2248x; 1.0878x over previous
//
#include <hip/hip_runtime.h>

#define IH 256
#define IW 256
#define FH 128
#define FW 128
#define NB 16
#define ICH 33
#define NF 10
#define NC 30            // warped channels = NF*3
#define PL (FH * FW)     // 16384
#define SPLIT 4                              // quarter-plane parts per (b,c)
#define LOSS_BLOCKS (NB * NC * SPLIT)        // 1920
#define SMOOTH_BLOCKS 240
#define HALO 7
#define SROWS (32 + 2 * HALO + 1)            // 47 rows staged -> 24064 B LDS (6 blocks/CU)
#define PART_STRIDE 8

// fast exact charbonnier: (g^2 + 1e-6)^0.4, arg > 0 so hw log2/exp2 safe (~1ulp)
__device__ __forceinline__ float charb(float g) {
    float t = fmaf(g, g, 1e-6f);
    return __builtin_amdgcn_exp2f(0.4f * __builtin_amdgcn_logf(t));
}

// align-corners bilinear sample of a 256x256 plane at 128-grid point (Y,X).
// Bit-exact vs jax reference (absmax 0.0, rounds 3-6).
__device__ __forceinline__ float resized_at(const float* __restrict__ plane, int Y, int X) {
    const float s = (float)(255.0 / 127.0);
    float fy = (float)Y * s;
    float fx = (float)X * s;
    int y0 = (int)fy; y0 = y0 > IH - 2 ? IH - 2 : y0;
    int x0 = (int)fx; x0 = x0 > IW - 2 ? IW - 2 : x0;
    float wy = fy - (float)y0;
    float wx = fx - (float)x0;
    const float* p0 = plane + y0 * IW + x0;
    float v00 = p0[0], v01 = p0[1];
    float v10 = p0[IW], v11 = p0[IW + 1];
    float r0 = v00 * (1.f - wy) + v10 * wy;   // y-interp first (matches reference)
    float r1 = v01 * (1.f - wy) + v11 * wy;
    return r0 * (1.f - wx) + r1 * wx;
}

// ============ Mega kernel: smooth (blocks [0,240)) + loss (blocks [240,2160)) ========
// No atomics, no zero-init: every block plain-stores its partial; finalize (separate
// dispatch = device-wide coherence point) combines.
__global__ void __launch_bounds__(256, 6) mega(const float* __restrict__ images,
                                               const float* __restrict__ flows,
                                               float* __restrict__ ws)
{
    float* part_loss   = ws;                                // [1920][8]
    float* part_smooth = ws + LOSS_BLOCKS * PART_STRIDE;    // [240]

    if (blockIdx.x < SMOOTH_BLOCKS) {
        // ---------- smoothness partial: gradient along flow-index axis and H axis ----
        int sb = blockIdx.x;
        const int total = NB * NF * PL;
        float s = 0.f;
        for (int i = sb * 256 + threadIdx.x; i < total; i += SMOOTH_BLOCKS * 256) {
            int w = i & (FW - 1);
            int h = (i >> 7) & (FH - 1);
            int f = (i >> 14) % NF;
            int b = i / (NF * PL);
            int pix = h * FW + w;
            const float* xp = flows + (size_t)(b * 2 * NF + 2 * f) * PL;
            const float* yp = xp + PL;

            float g1x, g1y;   // flow-channel axis (stride 2 planes)
            if (f == 0)           { g1x = xp[2 * PL + pix] - xp[pix];
                                    g1y = yp[2 * PL + pix] - yp[pix]; }
            else if (f == NF - 1) { g1x = xp[pix] - xp[pix - 2 * PL];
                                    g1y = yp[pix] - yp[pix - 2 * PL]; }
            else                  { g1x = 0.5f * (xp[2 * PL + pix] - xp[pix - 2 * PL]);
                                    g1y = 0.5f * (yp[2 * PL + pix] - yp[pix - 2 * PL]); }

            float g2x, g2y;   // H axis
            if (h == 0)           { g2x = xp[pix + FW] - xp[pix];
                                    g2y = yp[pix + FW] - yp[pix]; }
            else if (h == FH - 1) { g2x = xp[pix] - xp[pix - FW];
                                    g2y = yp[pix] - yp[pix - FW]; }
            else                  { g2x = 0.5f * (xp[pix + FW] - xp[pix - FW]);
                                    g2y = 0.5f * (yp[pix + FW] - yp[pix - FW]); }

            s += charb(g1x) + charb(g2x) + charb(g1y) + charb(g2y);
        }
        for (int off = 32; off > 0; off >>= 1) s += __shfl_down(s, off, 64);
        __shared__ float shs[4];
        int wave = threadIdx.x >> 6;
        if ((threadIdx.x & 63) == 0) shs[wave] = s;
        __syncthreads();
        if (threadIdx.x == 0)
            part_smooth[sb] = shs[0] + shs[1] + shs[2] + shs[3];
        return;
    }

    // ---------- loss block: (bc, quarter-plane part p) ----------
    __shared__ float slds[SROWS * FW];     // resized src quarter-plane + halo
    int blk = blockIdx.x - SMOOTH_BLOCKS;  // 0..1919
    int bc = blk >> 2;
    int p  = blk & 3;
    int b = bc / NC;
    int c = bc % NC;
    int f = c / 3;
    const float* ref_img  = images + (size_t)(b * ICH + c) * (IH * IW);
    const float* src_img  = images + (size_t)(b * ICH + 3 + c) * (IH * IW);
    const float* fx_plane = flows + (size_t)(b * 2 * NF + 2 * f) * PL;
    const float* fy_plane = fx_plane + PL;

    int lo = p * 32 - HALO;          if (lo < 0) lo = 0;
    int hi = p * 32 + 31 + HALO + 1; if (hi > FH - 1) hi = FH - 1;
    int nstage = (hi - lo + 1) * FW;

    // stage: resize src rows [lo,hi] into LDS (iterations independent -> ILP)
    #pragma unroll 2
    for (int i = threadIdx.x; i < nstage; i += 256) {
        int y = lo + (i >> 7);
        int x = i & (FW - 1);
        slds[i] = resized_at(src_img, y, x);
    }
    __syncthreads();

    // per-thread w-pair is loop-invariant: hoist all x-side resize weights
    const float sR = (float)(255.0 / 127.0);
    int w0 = (2 * threadIdx.x) & (FW - 1);          // pixels w0, w0+1
    float fx0 = (float)w0 * sR;
    float fx1 = (float)(w0 + 1) * sR;
    int x00 = (int)fx0; if (x00 > IW - 2) x00 = IW - 2;
    int x01 = (int)fx1; if (x01 > IW - 2) x01 = IW - 2;
    float wxr0 = fx0 - (float)x00;
    float wxr1 = fx1 - (float)x01;

    float s_ref = 0.f, s_w = 0.f, s_r2 = 0.f, s_w2 = 0.f, s_rw = 0.f, s_pix = 0.f;
    int base2 = p * 2048;                            // float2 pixel-pair index base
    for (int i = threadIdx.x; i < 2048; i += 256) {
        int p2 = base2 + i;
        int px = 2 * p2;
        int h = px >> 7;
        // --- ref resize, both pixels: 8 independent global loads, hoisted x-weights
        float fyR = (float)h * sR;
        int yr0 = (int)fyR; if (yr0 > IH - 2) yr0 = IH - 2;
        float wyr = fyR - (float)yr0;
        const float* rp0 = ref_img + yr0 * IW;
        const float* rp1 = rp0 + IW;
        float a00 = rp0[x00], a01 = rp0[x00 + 1], a10 = rp1[x00], a11 = rp1[x00 + 1];
        float b00 = rp0[x01], b01 = rp0[x01 + 1], b10 = rp1[x01], b11 = rp1[x01 + 1];
        float2 fl_x = ((const float2*)fx_plane)[p2];
        float2 fl_y = ((const float2*)fy_plane)[p2];

        float ar0 = a00 * (1.f - wyr) + a10 * wyr;
        float ar1 = a01 * (1.f - wyr) + a11 * wyr;
        float ref0 = ar0 * (1.f - wxr0) + ar1 * wxr0;
        float br0 = b00 * (1.f - wyr) + b10 * wyr;
        float br1 = b01 * (1.f - wyr) + b11 * wyr;
        float ref1 = br0 * (1.f - wxr1) + br1 * wxr1;

        // --- warp sample from LDS, both pixels
        float wv[2];
        #pragma unroll
        for (int q = 0; q < 2; q++) {
            float gx = (float)(w0 + q) + (q ? fl_x.y : fl_x.x);
            float gy = (float)h + (q ? fl_y.y : fl_y.x);
            float x0f = floorf(gx), y0f = floorf(gy);
            float wx = gx - x0f, wy = gy - y0f;
            int x0 = (int)x0f; x0 = min(max(x0, 0), FW - 1);
            int y0 = (int)y0f; y0 = min(max(y0, 0), FH - 1);
            int x1 = min(x0 + 1, FW - 1);
            int y1 = min(y0 + 1, FH - 1);
            float v00, v01, v10, v11;
            if (y0 >= lo && y1 <= hi) {     // true unless |flow| > 7 sigma
                const float* r0 = slds + ((y0 - lo) << 7);
                const float* r1 = slds + ((y1 - lo) << 7);
                v00 = r0[x0]; v01 = r0[x1];
                v10 = r1[x0]; v11 = r1[x1];
            } else {                         // exact recompute from global (rare)
                v00 = resized_at(src_img, y0, x0);
                v01 = resized_at(src_img, y0, x1);
                v10 = resized_at(src_img, y1, x0);
                v11 = resized_at(src_img, y1, x1);
            }
            float top = v00 * (1.f - wx) + v01 * wx;
            float bot = v10 * (1.f - wx) + v11 * wx;
            wv[q] = top * (1.f - wy) + bot * wy;
        }

        s_ref += ref0 + ref1;
        s_w   += wv[0] + wv[1];
        s_r2  += ref0 * ref0 + ref1 * ref1;
        s_w2  += wv[0] * wv[0] + wv[1] * wv[1];
        s_rw  += ref0 * wv[0] + ref1 * wv[1];
        s_pix += charb(ref0 - wv[0]) + charb(ref1 - wv[1]);
    }
    for (int off = 32; off > 0; off >>= 1) {
        s_ref += __shfl_down(s_ref, off, 64);
        s_w   += __shfl_down(s_w, off, 64);
        s_r2  += __shfl_down(s_r2, off, 64);
        s_w2  += __shfl_down(s_w2, off, 64);
        s_rw  += __shfl_down(s_rw, off, 64);
        s_pix += __shfl_down(s_pix, off, 64);
    }
    __shared__ float sh[4][6];
    int wave = threadIdx.x >> 6;
    if ((threadIdx.x & 63) == 0) {
        sh[wave][0] = s_ref; sh[wave][1] = s_w; sh[wave][2] = s_r2;
        sh[wave][3] = s_w2;  sh[wave][4] = s_rw; sh[wave][5] = s_pix;
    }
    __syncthreads();
    if (threadIdx.x < 6) {
        int k = threadIdx.x;
        part_loss[blk * PART_STRIDE + k] = sh[0][k] + sh[1][k] + sh[2][k] + sh[3][k];
    }
}

// ============ finalize: SSIM per (b,c) + combine to scalar ============
__global__ void __launch_bounds__(512) finalize2(const float* __restrict__ ws,
                                                 float* __restrict__ out)
{
    const float* part_loss   = ws;
    const float* part_smooth = ws + LOSS_BLOCKS * PART_STRIDE;
    int tid = threadIdx.x;
    float ssim = 0.f, pix = 0.f, smo = 0.f;
    if (tid < NB * NC) {
        float t0 = 0, t1 = 0, t2 = 0, t3 = 0, t4 = 0;
        for (int q = 0; q < SPLIT; q++) {
            const float* a = part_loss + (SPLIT * tid + q) * PART_STRIDE;
            t0 += a[0]; t1 += a[1]; t2 += a[2]; t3 += a[3]; t4 += a[4];
            pix += a[5];
        }
        const float N = (float)PL;
        float mu1 = t0 / N, mu2 = t1 / N;
        float var1 = (t2 - t0 * mu1) / (N - 1.f);
        float var2 = (t3 - t1 * mu2) / (N - 1.f);
        float s12 = t4 / N - mu1 * mu2;
        float num = (2.f * mu1 * mu2 + 1e-4f) * (2.f * s12 + 1e-3f);
        float den = (mu1 * mu1 + mu2 * mu2 + 1e-4f) * (var1 + var2 + 1e-3f);
        ssim = num / den;
    }
    if (tid < SMOOTH_BLOCKS) smo = part_smooth[tid];
    __shared__ float sa[512], sb[512], sc[512];
    sa[tid] = ssim; sb[tid] = pix; sc[tid] = smo;
    __syncthreads();
    for (int off = 256; off > 0; off >>= 1) {
        if (tid < off) {
            sa[tid] += sa[tid + off];
            sb[tid] += sb[tid + off];
            sc[tid] += sc[tid + off];
        }
        __syncthreads();
    }
    if (tid == 0) {
        out[0] = sb[0] / (float)(NB * NC * PL)
               + 0.01f * (sc[0] / (float)(NB * NF * PL))
               + sa[0] / (float)(NB * NC);
    }
}

extern "C" void kernel_launch(void* const* d_in, const int* in_sizes, int n_in,
                              void* d_out, int out_size, void* d_ws, size_t ws_size,
                              hipStream_t stream) {
    const float* images = (const float*)d_in[0];
    const float* flows  = (const float*)d_in[1];
    float* ws = (float*)d_ws;   // ~62 KB of plain-stored partials
    mega<<<SMOOTH_BLOCKS + LOSS_BLOCKS, 256, 0, stream>>>(images, flows, ws);
    finalize2<<<1, 512, 0, stream>>>(ws, (float*)d_out);
}